// Round 2
// baseline (1586.883 us; speedup 1.0000x reference)
//
#include <hip/hip_runtime.h>

typedef float f4 __attribute__((ext_vector_type(4)));
typedef int   i4 __attribute__((ext_vector_type(4)));

#define NOFF 18
#define NCH  8     // K-chunks
#define CCH  16    // channels per chunk
#define FL   144   // CCH*9 flats per chunk
#define NQ   36    // FL/4

// Fused deformable conv: one block = 32 output pixels (half a row), 128 threads.
// Phase 1: regular 3x3 conv (C=128 -> 18 offset channels) for these 32 px.
// Phase 2: bilinear-sample + contract to 128 output channels.
__global__ __launch_bounds__(128) void dcn_fused(
    const float* __restrict__ xg, const float* __restrict__ w_off,
    const float* __restrict__ b_off, const float* __restrict__ w_dcn,
    float* __restrict__ out)
{
  __shared__ __align__(16) float s_lds[FL * 32];        // 18.4 KB samples (both phases)
  __shared__ __align__(16) char  s_ovl[NOFF * FL * 4];  // 10.4 KB: s_w (ph1) / idxT+wtT (ph2)
  __shared__ __align__(16) float offT[NOFF * 32];       // 2.3 KB offsets
  __shared__ int   idxI[9 * 32];                        // integer im2col tables (ph1)
  __shared__ float wtI [9 * 32];

  float*    s_w  = (float*)s_ovl;
  const f4* s_w4 = (const f4*)s_ovl;
  i4* idxT = (i4*)s_ovl;                 // 288*16 = 4608 B
  f4* wtT  = (f4*)(s_ovl + 4608);        // 288*16 = 4608 B  (9216 <= 10368)

  const int tid = threadIdx.x;
  const int p0  = blockIdx.x * 32;
  const int b   = p0 >> 12;
  const int ho  = (p0 >> 6) & 63;
  const int wo0 = p0 & 63;               // 0 or 32
  const int og  = tid & 15;
  const int pxq = tid >> 4;              // px = pxq*4 + p

  // ---- integer im2col tables for phase 1 ----
  for (int kp = tid; kp < 9 * 32; kp += 128) {
    int k = kp >> 5, px = kp & 31;
    int ky = k / 3, kx = k - ky * 3;
    int iy = ho - 1 + ky;
    int ix = wo0 + px - 1 + kx;
    bool v = ((unsigned)iy < 64u) && ((unsigned)ix < 64u);
    idxI[kp] = v ? (iy * 64 + ix) : 0;
    wtI [kp] = v ? 1.f : 0.f;
  }

  // offset accumulators: thread (og,pxq) owns o = og and o = og+16 (if <18), 4 px
  float accP[2][4];
  {
    float b0 = b_off[og];
    float b1 = (og < 2) ? b_off[og + 16] : 0.f;
    #pragma unroll
    for (int p = 0; p < 4; ++p) { accP[0][p] = b0; accP[1][p] = b1; }
  }

  const float* xb_base = xg + ((size_t)b << 19);   // b * 128 * 4096

  // ================= Phase 1: offset conv =================
  for (int ch = 0; ch < NCH; ++ch) {
    __syncthreads();  // tables ready (iter 0) / prior readers of s_lds+s_w done
    const float* xb0 = xb_base + (ch * CCH << 12);
    for (int j = 0; j < 36; ++j) {
      int s  = j * 128 + tid;
      int px = s & 31, r = s >> 5;       // r = cl*9 + k
      int cl = r / 9;
      int k  = r - cl * 9;
      int kp = (k << 5) + px;
      s_lds[r * 32 + px] = wtI[kp] * xb0[(cl << 12) + idxI[kp]];
    }
    for (int i = tid; i < NOFF * NQ; i += 128) {   // stage w_off chunk: 648 f4
      int o = i / NQ, qq = i - o * NQ;
      ((f4*)s_w)[o * NQ + qq] = ((const f4*)w_off)[o * 288 + ch * NQ + qq];
    }
    __syncthreads();
    for (int q = 0; q < NQ; ++q) {
      f4 w0 = s_w4[og * NQ + q];
      f4 w1 = (og < 2) ? s_w4[(og + 16) * NQ + q] : f4{0.f, 0.f, 0.f, 0.f};
      #pragma unroll
      for (int e = 0; e < 4; ++e) {
        f4 sv = *(const f4*)&s_lds[(q * 4 + e) * 32 + pxq * 4];
        #pragma unroll
        for (int p = 0; p < 4; ++p) {
          accP[0][p] += sv[p] * w0[e];
          accP[1][p] += sv[p] * w1[e];
        }
      }
    }
  }

  // write offsets to LDS
  {
    f4 r0; r0[0] = accP[0][0]; r0[1] = accP[0][1]; r0[2] = accP[0][2]; r0[3] = accP[0][3];
    *(f4*)&offT[og * 32 + pxq * 4] = r0;
    if (og < 2) {
      f4 r1; r1[0] = accP[1][0]; r1[1] = accP[1][1]; r1[2] = accP[1][2]; r1[3] = accP[1][3];
      *(f4*)&offT[(og + 16) * 32 + pxq * 4] = r1;
    }
  }
  __syncthreads();  // offT visible; all s_w readers done (idxT/wtT alias s_w)

  // ---- bilinear corner tables from offT ----
  for (int kp = tid; kp < 9 * 32; kp += 128) {
    int k  = kp >> 5, px = kp & 31;
    int wo = wo0 + px;
    int ky = k / 3, kx = k - ky * 3;
    float dy = offT[(2 * k    ) * 32 + px];
    float dx = offT[(2 * k + 1) * 32 + px];
    float y = (float)(ho - 1 + ky) + dy;
    float x = (float)(wo - 1 + kx) + dx;
    float y0f = floorf(y), x0f = floorf(x);
    float wy = y - y0f,    wx = x - x0f;
    int y0 = (int)y0f, x0 = (int)x0f;
    int y1 = y0 + 1,   x1 = x0 + 1;
    int cy0 = min(max(y0, 0), 63), cx0 = min(max(x0, 0), 63);
    int cy1 = min(max(y1, 0), 63), cx1 = min(max(x1, 0), 63);
    float vy0 = ((unsigned)y0 < 64u) ? 1.f : 0.f;
    float vy1 = ((unsigned)y1 < 64u) ? 1.f : 0.f;
    float vx0 = ((unsigned)x0 < 64u) ? 1.f : 0.f;
    float vx1 = ((unsigned)x1 < 64u) ? 1.f : 0.f;
    i4 iv; iv[0] = cy0*64+cx0; iv[1] = cy0*64+cx1; iv[2] = cy1*64+cx0; iv[3] = cy1*64+cx1;
    f4 wv;
    wv[0] = (1.f - wy) * (1.f - wx) * vy0 * vx0;
    wv[1] = (1.f - wy) * wx         * vy0 * vx1;
    wv[2] = wy         * (1.f - wx) * vy1 * vx0;
    wv[3] = wy         * wx         * vy1 * vx1;
    idxT[kp] = iv;
    wtT [kp] = wv;
  }

  // ================= Phase 2: sample + contract =================
  float acc[8][4];
  #pragma unroll
  for (int oi = 0; oi < 8; ++oi)
    #pragma unroll
    for (int p = 0; p < 4; ++p) acc[oi][p] = 0.f;

  const f4* wd4 = (const f4*)w_dcn;   // [128][288] f4
  for (int ch = 0; ch < NCH; ++ch) {
    __syncthreads();  // tables ready (iter 0) / prior s_lds readers done
    const float* xb0 = xb_base + (ch * CCH << 12);
    for (int j = 0; j < 36; ++j) {
      int s  = j * 128 + tid;
      int px = s & 31, r = s >> 5;
      int cl = r / 9;
      int k  = r - cl * 9;
      int kp = (k << 5) + px;
      i4 iv = idxT[kp];
      f4 wv = wtT[kp];
      const float* xb = xb0 + (cl << 12);
      s_lds[r * 32 + px] =
          wv[0] * xb[iv[0]] + wv[1] * xb[iv[1]] +
          wv[2] * xb[iv[2]] + wv[3] * xb[iv[3]];
    }
    __syncthreads();
    for (int q = 0; q < NQ; ++q) {
      f4 wq[8];
      #pragma unroll
      for (int oi = 0; oi < 8; ++oi)
        wq[oi] = wd4[(og * 8 + oi) * 288 + ch * NQ + q];
      #pragma unroll
      for (int e = 0; e < 4; ++e) {
        f4 sv = *(const f4*)&s_lds[(q * 4 + e) * 32 + pxq * 4];
        #pragma unroll
        for (int oi = 0; oi < 8; ++oi)
          #pragma unroll
          for (int p = 0; p < 4; ++p)
            acc[oi][p] += sv[p] * wq[oi][e];
      }
    }
  }

  #pragma unroll
  for (int oi = 0; oi < 8; ++oi) {
    int o = og * 8 + oi;
    f4 r; r[0] = acc[oi][0]; r[1] = acc[oi][1]; r[2] = acc[oi][2]; r[3] = acc[oi][3];
    *(f4*)&out[(((size_t)b * 128 + o) * 64 + ho) * 64 + wo0 + pxq * 4] = r;
  }
}

extern "C" void kernel_launch(void* const* d_in, const int* in_sizes, int n_in,
                              void* d_out, int out_size, void* d_ws, size_t ws_size,
                              hipStream_t stream) {
  const float* x     = (const float*)d_in[0];
  const float* w_off = (const float*)d_in[1];
  const float* b_off = (const float*)d_in[2];
  const float* w_dcn = (const float*)d_in[3];
  float* out = (float*)d_out;

  hipLaunchKernelGGL(dcn_fused, dim3(1024), dim3(128), 0, stream,
                     x, w_off, b_off, w_dcn, out);
}

// Round 5
// 143.849 us; speedup vs baseline: 11.0316x; 11.0316x over previous
//
#include <hip/hip_runtime.h>

typedef float f32x4 __attribute__((ext_vector_type(4)));
typedef int   i32x4 __attribute__((ext_vector_type(4)));
typedef short b16x8 __attribute__((ext_vector_type(8)));

__device__ __forceinline__ short f2b(float v) {   // f32 -> bf16 (RNE)
  union { float f; unsigned u; } x; x.f = v;
  unsigned r = x.u + 0x7FFFu + ((x.u >> 16) & 1u);
  return (short)(r >> 16);
}

#define WT_ELEMS   (9 * 128 * 128)   // wT[k][o][c]
#define WOFF_ELEMS (9 * 32 * 128)    // wOffT[k][o(pad32)][c]

// ---- prep: reorder weights to tap-major bf16 in workspace ----
__global__ __launch_bounds__(256) void prep_w(
    const float* __restrict__ w_off, const float* __restrict__ w_dcn,
    short* __restrict__ wT, short* __restrict__ wOffT)
{
  int t = blockIdx.x * 256 + threadIdx.x;
  int stride = gridDim.x * 256;
  for (int i = t; i < WT_ELEMS; i += stride) {
    int k = i >> 14, r = i & 16383, o = r >> 7, c = r & 127;
    wT[i] = f2b(w_dcn[o * 1152 + c * 9 + k]);
  }
  for (int i = t; i < WOFF_ELEMS; i += stride) {
    int k = i >> 12, r = i & 4095, o = r >> 7, c = r & 127;
    wOffT[i] = (o < 18) ? f2b(w_off[o * 1152 + c * 9 + k]) : (short)0;
  }
}

// ---- fused deformable conv, MFMA ----
// block = 32 px (b, ho, wo0..wo0+31), 256 threads = 4 waves.
// K ordered tap-major: per tap k, contract 128 channels (4 MFMA K-steps).
__global__ __launch_bounds__(256) void dcn_mfma(
    const float* __restrict__ xg, const float* __restrict__ b_off,
    const short* __restrict__ wT, const short* __restrict__ wOffT,
    float* __restrict__ out)
{
  __shared__ __align__(16) char  sS[32 * 256];   // S[px][c] bf16, XOR-swizzled rows
  __shared__ __align__(16) float offT[32 * 32];  // offsets [o(pad32)][px]
  __shared__ __align__(16) i32x4 idxT[32];
  __shared__ __align__(16) f32x4 wtT[32];

  const int tid  = threadIdx.x;
  const int lane = tid & 63;
  const int wv_  = tid >> 6;       // wave 0..3
  const int bid  = blockIdx.x;
  const int swz  = (bid & 7) * 128 + (bid >> 3);   // XCD-chunked: batch b -> one XCD
  const int b    = swz >> 7;
  const int ho   = (swz >> 1) & 63;
  const int wo0  = (swz & 1) * 32;

  const int px_s = tid & 31;       // sampling: pixel
  const int cg   = tid >> 5;       // sampling: c-group 0..7
  const int l15  = lane & 15;
  const int l4   = lane >> 4;

  const float* xb = xg + ((size_t)b << 19);   // x[b]: 128 * 4096 floats

  // ================= Phase 1: offset conv (integer taps) =================
  f32x4 accP = {0.f, 0.f, 0.f, 0.f};
  const int fo = wv_ >> 1;         // o-frag (0:o0-15, 1:o16-31)
  const int fp = wv_ & 1;          // px-group (0:px0-15, 1:px16-31)

  for (int k = 0; k < 9; ++k) {
    int ky = k / 3, kx = k - ky * 3;
    __syncthreads();               // prior readers of sS done
    {
      int iy = ho - 1 + ky;
      int ix = wo0 + px_s - 1 + kx;
      bool v = ((unsigned)iy < 64u) && ((unsigned)ix < 64u);
      const float* xr = xb + iy * 64 + ix;
      #pragma unroll
      for (int it = 0; it < 2; ++it) {
        int cb = (cg + it * 8) * 8;                 // 8 consecutive channels
        const float* xc = xr + ((size_t)cb << 12);
        b16x8 pk;
        #pragma unroll
        for (int j = 0; j < 8; ++j) {
          float val = v ? xc[(size_t)j << 12] : 0.f;
          pk[j] = f2b(val);
        }
        *(b16x8*)(sS + px_s * 256 + ((cb * 2) ^ ((px_s & 7) << 4))) = pk;
      }
    }
    __syncthreads();               // sS ready
    const short* wk = wOffT + k * (32 * 128);
    int bpx = fp * 16 + l15;
    #pragma unroll
    for (int kk = 0; kk < 4; ++kk) {
      int cf = kk * 32 + l4 * 8;
      b16x8 a  = *(const b16x8*)(wk + (fo * 16 + l15) * 128 + cf);
      b16x8 bb = *(const b16x8*)(sS + bpx * 256 + ((cf * 2) ^ ((bpx & 7) << 4)));
      accP = __builtin_amdgcn_mfma_f32_16x16x32_bf16(a, bb, accP, 0, 0, 0);
    }
  }
  {
    int px = fp * 16 + l15;
    int ob = fo * 16 + l4 * 4;
    #pragma unroll
    for (int r = 0; r < 4; ++r)
      offT[(ob + r) * 32 + px] = accP[r];
  }
  __syncthreads();                 // offT visible; phase-1 sS readers done

  // ================= Phase 2: bilinear sample + contract =================
  f32x4 acc00 = {0,0,0,0}, acc01 = {0,0,0,0}, acc10 = {0,0,0,0}, acc11 = {0,0,0,0};

  for (int k = 0; k < 9; ++k) {
    int ky = k / 3, kx = k - ky * 3;
    if (tid < 32) {                // bilinear tables for this tap
      int px = tid;
      float dy = offT[(2 * k) * 32 + px]     + b_off[2 * k];
      float dx = offT[(2 * k + 1) * 32 + px] + b_off[2 * k + 1];
      float yy = (float)(ho - 1 + ky) + dy;
      float xx = (float)(wo0 + px - 1 + kx) + dx;
      float y0f = floorf(yy), x0f = floorf(xx);
      float wy = yy - y0f, wx = xx - x0f;
      int y0 = (int)y0f, x0 = (int)x0f;
      int y1 = y0 + 1, x1 = x0 + 1;
      int cy0 = min(max(y0, 0), 63), cx0 = min(max(x0, 0), 63);
      int cy1 = min(max(y1, 0), 63), cx1 = min(max(x1, 0), 63);
      float vy0 = ((unsigned)y0 < 64u) ? 1.f : 0.f;
      float vy1 = ((unsigned)y1 < 64u) ? 1.f : 0.f;
      float vx0 = ((unsigned)x0 < 64u) ? 1.f : 0.f;
      float vx1 = ((unsigned)x1 < 64u) ? 1.f : 0.f;
      i32x4 iv; iv[0] = cy0*64+cx0; iv[1] = cy0*64+cx1; iv[2] = cy1*64+cx0; iv[3] = cy1*64+cx1;
      f32x4 wvv;
      wvv[0] = (1.f - wy) * (1.f - wx) * vy0 * vx0;
      wvv[1] = (1.f - wy) * wx         * vy0 * vx1;
      wvv[2] = wy         * (1.f - wx) * vy1 * vx0;
      wvv[3] = wy         * wx         * vy1 * vx1;
      idxT[px] = iv; wtT[px] = wvv;
    }
    __syncthreads();               // tables ready; prior sS readers done
    i32x4 iv  = idxT[px_s];
    f32x4 wvv = wtT[px_s];
    #pragma unroll
    for (int it = 0; it < 2; ++it) {
      int cb = (cg + it * 8) * 8;
      const float* xc = xb + ((size_t)cb << 12);
      b16x8 pk;
      #pragma unroll
      for (int j = 0; j < 8; ++j) {
        const float* p = xc + ((size_t)j << 12);
        float v = wvv[0] * p[iv[0]] + wvv[1] * p[iv[1]] +
                  wvv[2] * p[iv[2]] + wvv[3] * p[iv[3]];
        pk[j] = f2b(v);
      }
      *(b16x8*)(sS + px_s * 256 + ((cb * 2) ^ ((px_s & 7) << 4))) = pk;
    }
    __syncthreads();               // sS ready
    const short* wk = wT + k * 16384 + (wv_ * 32) * 128;   // wave's 32-o slice
    #pragma unroll
    for (int kk = 0; kk < 4; ++kk) {
      int cf = kk * 32 + l4 * 8;
      b16x8 a0 = *(const b16x8*)(wk + l15 * 128 + cf);
      b16x8 a1 = *(const b16x8*)(wk + (l15 + 16) * 128 + cf);
      b16x8 b0 = *(const b16x8*)(sS + l15 * 256        + ((cf * 2) ^ ((l15 & 7) << 4)));
      b16x8 b1 = *(const b16x8*)(sS + (16 + l15) * 256 + ((cf * 2) ^ ((l15 & 7) << 4)));
      acc00 = __builtin_amdgcn_mfma_f32_16x16x32_bf16(a0, b0, acc00, 0, 0, 0);
      acc01 = __builtin_amdgcn_mfma_f32_16x16x32_bf16(a0, b1, acc01, 0, 0, 0);
      acc10 = __builtin_amdgcn_mfma_f32_16x16x32_bf16(a1, b0, acc10, 0, 0, 0);
      acc11 = __builtin_amdgcn_mfma_f32_16x16x32_bf16(a1, b1, acc11, 0, 0, 0);
    }
  }

  // epilogue: D row = l4*4+r (o), col = l15 (px)
  {
    size_t base = ((size_t)b * 128) * 4096 + (size_t)ho * 64 + wo0;
    int o0 = wv_ * 32 + l4 * 4;
    #pragma unroll
    for (int r = 0; r < 4; ++r) {
      out[base + (size_t)(o0 + r) * 4096 + l15]           = acc00[r];
      out[base + (size_t)(o0 + r) * 4096 + 16 + l15]      = acc01[r];
      out[base + (size_t)(o0 + 16 + r) * 4096 + l15]      = acc10[r];
      out[base + (size_t)(o0 + 16 + r) * 4096 + 16 + l15] = acc11[r];
    }
  }
}

extern "C" void kernel_launch(void* const* d_in, const int* in_sizes, int n_in,
                              void* d_out, int out_size, void* d_ws, size_t ws_size,
                              hipStream_t stream) {
  const float* x     = (const float*)d_in[0];
  const float* w_off = (const float*)d_in[1];
  const float* b_off = (const float*)d_in[2];
  const float* w_dcn = (const float*)d_in[3];
  float* out = (float*)d_out;

  short* wT    = (short*)d_ws;                       // 294,912 B
  short* wOffT = (short*)((char*)d_ws + WT_ELEMS * 2); // 73,728 B  (total 368,640 <= ws)

  hipLaunchKernelGGL(prep_w,   dim3(64),   dim3(256), 0, stream, w_off, w_dcn, wT, wOffT);
  hipLaunchKernelGGL(dcn_mfma, dim3(1024), dim3(256), 0, stream, x, b_off, wT, wOffT, out);
}

// Round 6
// 79.387 us; speedup vs baseline: 19.9892x; 1.8120x over previous
//
#include <hip/hip_runtime.h>

typedef float f32x4 __attribute__((ext_vector_type(4)));
typedef int   i32x4 __attribute__((ext_vector_type(4)));
typedef short b16x8 __attribute__((ext_vector_type(8)));

__device__ __forceinline__ short f2b(float v) {   // f32 -> bf16 (RNE)
  union { float f; unsigned u; } x; x.f = v;
  unsigned r = x.u + 0x7FFFu + ((x.u >> 16) & 1u);
  return (short)(r >> 16);
}
__device__ __forceinline__ float b2f(short s) {   // bf16 -> f32
  union { unsigned u; float f; } x; x.u = ((unsigned)(unsigned short)s) << 16;
  return x.f;
}

#define WT_ELEMS   (9 * 128 * 128)     // wT[k][o][c]
#define WOFF_ELEMS (9 * 32 * 128)      // wOffT[k][o(pad32)][c]
#define XT_BYTES   (8u * 4096u * 128u * 2u)   // x_t[b][y*64+x][c] bf16 = 8 MB

// ---- prep: reorder weights to tap-major bf16 ----
__global__ __launch_bounds__(256) void prep_w(
    const float* __restrict__ w_off, const float* __restrict__ w_dcn,
    short* __restrict__ wT, short* __restrict__ wOffT)
{
  int t = blockIdx.x * 256 + threadIdx.x;
  int stride = gridDim.x * 256;
  for (int i = t; i < WT_ELEMS; i += stride) {
    int k = i >> 14, r = i & 16383, o = r >> 7, c = r & 127;
    wT[i] = f2b(w_dcn[o * 1152 + c * 9 + k]);
  }
  for (int i = t; i < WOFF_ELEMS; i += stride) {
    int k = i >> 12, r = i & 4095, o = r >> 7, c = r & 127;
    wOffT[i] = (o < 18) ? f2b(w_off[o * 1152 + c * 9 + k]) : (short)0;
  }
}

// ---- transpose x[b][c][y][w] f32 -> x_t[b][y][w][c] bf16 ----
// block = one (b,y) row; LDS tile [32][65] (padded, conflict-checked).
__global__ __launch_bounds__(256) void transp(
    const float* __restrict__ xg, short* __restrict__ xt)
{
  __shared__ float tile[32][65];
  const int bid = blockIdx.x;
  const int b = bid >> 6, y = bid & 63;
  const int t = threadIdx.x;
  const float* src = xg + ((size_t)b << 19) + y * 64;          // + c*4096 + w
  short*       dst = xt + ((size_t)b << 19) + (size_t)y * 8192; // + w*128 + c

  for (int ct = 0; ct < 4; ++ct) {
    __syncthreads();                       // prior readers done
    int c_l = t >> 3, w0 = (t & 7) * 8;
    const float* p = src + (size_t)(ct * 32 + c_l) * 4096 + w0;
    f32x4 a0 = *(const f32x4*)p;
    f32x4 a1 = *(const f32x4*)(p + 4);
    #pragma unroll
    for (int i = 0; i < 4; ++i) { tile[c_l][w0 + i] = a0[i]; tile[c_l][w0 + 4 + i] = a1[i]; }
    __syncthreads();                       // tile ready
    int w = t >> 2, j0 = (t & 3) * 8;
    b16x8 pk;
    #pragma unroll
    for (int j = 0; j < 8; ++j) pk[j] = f2b(tile[j0 + j][w]);
    *(b16x8*)(dst + w * 128 + ct * 32 + j0) = pk;
  }
}

// ---- fused deformable conv, MFMA, channel-last sampling ----
// block = 32 px (b, ho, wo0..wo0+31), 256 threads = 4 waves.
__global__ __launch_bounds__(256) void dcn_mfma(
    const short* __restrict__ xt, const float* __restrict__ b_off,
    const short* __restrict__ wT, const short* __restrict__ wOffT,
    float* __restrict__ out)
{
  __shared__ __align__(16) char  sS[32 * 256];   // S[px][c] bf16, XOR-swizzled rows
  __shared__ __align__(16) float offT[32 * 32];  // offsets [o(pad32)][px]
  __shared__ __align__(16) i32x4 idxT[32];
  __shared__ __align__(16) f32x4 wtT[32];

  const int tid  = threadIdx.x;
  const int lane = tid & 63;
  const int wv_  = tid >> 6;       // wave 0..3
  const int bid  = blockIdx.x;
  const int swz  = (bid & 7) * 128 + (bid >> 3);   // batch b -> one XCD (L2 locality)
  const int b    = swz >> 7;
  const int ho   = (swz >> 1) & 63;
  const int wo0  = (swz & 1) * 32;

  const int px_s = tid >> 3;       // sampling: pixel 0..31
  const int cg   = tid & 7;        // sampling: channel-group (8 ch per it-load)
  const int l15  = lane & 15;
  const int l4   = lane >> 4;

  const short* xb = xt + ((size_t)b << 19);   // x_t[b]: 4096*128 bf16

  // ================= Phase 1: offset conv (integer taps) =================
  f32x4 accP = {0.f, 0.f, 0.f, 0.f};
  const int fo = wv_ >> 1;         // o-frag (0:o0-15, 1:o16-31)
  const int fp = wv_ & 1;          // px-group (0:px0-15, 1:px16-31)

  for (int k = 0; k < 9; ++k) {
    int ky = k / 3, kx = k - ky * 3;
    __syncthreads();               // prior readers of sS done
    {
      int iy = ho - 1 + ky;
      int ix = wo0 + px_s - 1 + kx;
      bool v = ((unsigned)iy < 64u) && ((unsigned)ix < 64u);
      int idx = v ? (iy * 64 + ix) : 0;
      const short* row = xb + (size_t)idx * 128;
      #pragma unroll
      for (int it = 0; it < 2; ++it) {
        int c0 = it * 64 + cg * 8;
        b16x8 q = *(const b16x8*)(row + c0);
        if (!v) q = (b16x8)0;
        *(b16x8*)(sS + px_s * 256 + ((c0 * 2) ^ ((px_s & 7) << 4))) = q;
      }
    }
    __syncthreads();               // sS ready
    const short* wk = wOffT + k * (32 * 128);
    int bpx = fp * 16 + l15;
    #pragma unroll
    for (int kk = 0; kk < 4; ++kk) {
      int cf = kk * 32 + l4 * 8;
      b16x8 a  = *(const b16x8*)(wk + (fo * 16 + l15) * 128 + cf);
      b16x8 bb = *(const b16x8*)(sS + bpx * 256 + ((cf * 2) ^ ((bpx & 7) << 4)));
      accP = __builtin_amdgcn_mfma_f32_16x16x32_bf16(a, bb, accP, 0, 0, 0);
    }
  }
  {
    int px = fp * 16 + l15;
    int ob = fo * 16 + l4 * 4;
    #pragma unroll
    for (int r = 0; r < 4; ++r)
      offT[(ob + r) * 32 + px] = accP[r];
  }
  __syncthreads();                 // offT visible; phase-1 sS readers done

  // ================= Phase 2: bilinear sample + contract =================
  f32x4 acc00 = {0,0,0,0}, acc01 = {0,0,0,0}, acc10 = {0,0,0,0}, acc11 = {0,0,0,0};

  for (int k = 0; k < 9; ++k) {
    int ky = k / 3, kx = k - ky * 3;
    if (tid < 32) {                // bilinear tables for this tap
      int px = tid;
      float dy = offT[(2 * k) * 32 + px]     + b_off[2 * k];
      float dx = offT[(2 * k + 1) * 32 + px] + b_off[2 * k + 1];
      float yy = (float)(ho - 1 + ky) + dy;
      float xx = (float)(wo0 + px - 1 + kx) + dx;
      float y0f = floorf(yy), x0f = floorf(xx);
      float wy = yy - y0f, wx = xx - x0f;
      int y0 = (int)y0f, x0 = (int)x0f;
      int y1 = y0 + 1, x1 = x0 + 1;
      int cy0 = min(max(y0, 0), 63), cx0 = min(max(x0, 0), 63);
      int cy1 = min(max(y1, 0), 63), cx1 = min(max(x1, 0), 63);
      float vy0 = ((unsigned)y0 < 64u) ? 1.f : 0.f;
      float vy1 = ((unsigned)y1 < 64u) ? 1.f : 0.f;
      float vx0 = ((unsigned)x0 < 64u) ? 1.f : 0.f;
      float vx1 = ((unsigned)x1 < 64u) ? 1.f : 0.f;
      i32x4 iv; iv[0] = cy0*64+cx0; iv[1] = cy0*64+cx1; iv[2] = cy1*64+cx0; iv[3] = cy1*64+cx1;
      f32x4 wvv;
      wvv[0] = (1.f - wy) * (1.f - wx) * vy0 * vx0;
      wvv[1] = (1.f - wy) * wx         * vy0 * vx1;
      wvv[2] = wy         * (1.f - wx) * vy1 * vx0;
      wvv[3] = wy         * wx         * vy1 * vx1;
      idxT[px] = iv; wtT[px] = wvv;
    }
    __syncthreads();               // tables ready; prior sS readers done
    {
      i32x4 iv  = idxT[px_s];
      f32x4 wvv = wtT[px_s];
      const short* r0 = xb + (size_t)iv[0] * 128;
      const short* r1 = xb + (size_t)iv[1] * 128;
      const short* r2 = xb + (size_t)iv[2] * 128;
      const short* r3 = xb + (size_t)iv[3] * 128;
      #pragma unroll
      for (int it = 0; it < 2; ++it) {
        int c0 = it * 64 + cg * 8;
        b16x8 q0 = *(const b16x8*)(r0 + c0);
        b16x8 q1 = *(const b16x8*)(r1 + c0);
        b16x8 q2 = *(const b16x8*)(r2 + c0);
        b16x8 q3 = *(const b16x8*)(r3 + c0);
        b16x8 pk;
        #pragma unroll
        for (int j = 0; j < 8; ++j) {
          float v = wvv[0] * b2f(q0[j]) + wvv[1] * b2f(q1[j]) +
                    wvv[2] * b2f(q2[j]) + wvv[3] * b2f(q3[j]);
          pk[j] = f2b(v);
        }
        *(b16x8*)(sS + px_s * 256 + ((c0 * 2) ^ ((px_s & 7) << 4))) = pk;
      }
    }
    __syncthreads();               // sS ready
    const short* wk = wT + k * 16384 + (wv_ * 32) * 128;   // wave's 32-o slice
    #pragma unroll
    for (int kk = 0; kk < 4; ++kk) {
      int cf = kk * 32 + l4 * 8;
      b16x8 a0 = *(const b16x8*)(wk + l15 * 128 + cf);
      b16x8 a1 = *(const b16x8*)(wk + (l15 + 16) * 128 + cf);
      b16x8 b0 = *(const b16x8*)(sS + l15 * 256        + ((cf * 2) ^ ((l15 & 7) << 4)));
      b16x8 b1 = *(const b16x8*)(sS + (16 + l15) * 256 + ((cf * 2) ^ ((l15 & 7) << 4)));
      acc00 = __builtin_amdgcn_mfma_f32_16x16x32_bf16(a0, b0, acc00, 0, 0, 0);
      acc01 = __builtin_amdgcn_mfma_f32_16x16x32_bf16(a0, b1, acc01, 0, 0, 0);
      acc10 = __builtin_amdgcn_mfma_f32_16x16x32_bf16(a1, b0, acc10, 0, 0, 0);
      acc11 = __builtin_amdgcn_mfma_f32_16x16x32_bf16(a1, b1, acc11, 0, 0, 0);
    }
  }

  // epilogue: D row = l4*4+r (o), col = l15 (px)
  {
    size_t base = ((size_t)b * 128) * 4096 + (size_t)ho * 64 + wo0;
    int o0 = wv_ * 32 + l4 * 4;
    #pragma unroll
    for (int r = 0; r < 4; ++r) {
      out[base + (size_t)(o0 + r) * 4096 + l15]           = acc00[r];
      out[base + (size_t)(o0 + r) * 4096 + 16 + l15]      = acc01[r];
      out[base + (size_t)(o0 + 16 + r) * 4096 + l15]      = acc10[r];
      out[base + (size_t)(o0 + 16 + r) * 4096 + 16 + l15] = acc11[r];
    }
  }
}

extern "C" void kernel_launch(void* const* d_in, const int* in_sizes, int n_in,
                              void* d_out, int out_size, void* d_ws, size_t ws_size,
                              hipStream_t stream) {
  const float* x     = (const float*)d_in[0];
  const float* w_off = (const float*)d_in[1];
  const float* b_off = (const float*)d_in[2];
  const float* w_dcn = (const float*)d_in[3];
  float* out = (float*)d_out;

  short* xt    = (short*)d_ws;                               // 8,388,608 B
  short* wT    = (short*)((char*)d_ws + XT_BYTES);           // 294,912 B
  short* wOffT = (short*)((char*)d_ws + XT_BYTES + WT_ELEMS * 2); // 73,728 B

  hipLaunchKernelGGL(prep_w,   dim3(64),   dim3(256), 0, stream, w_off, w_dcn, wT, wOffT);
  hipLaunchKernelGGL(transp,   dim3(512),  dim3(256), 0, stream, x, xt);
  hipLaunchKernelGGL(dcn_mfma, dim3(1024), dim3(256), 0, stream, xt, b_off, wT, wOffT, out);
}

// Round 7
// 78.147 us; speedup vs baseline: 20.3065x; 1.0159x over previous
//
#include <hip/hip_runtime.h>

typedef float f32x4 __attribute__((ext_vector_type(4)));
typedef int   i32x4 __attribute__((ext_vector_type(4)));
typedef short b16x8 __attribute__((ext_vector_type(8)));

__device__ __forceinline__ short f2b(float v) {   // f32 -> bf16 (RNE)
  union { float f; unsigned u; } x; x.f = v;
  unsigned r = x.u + 0x7FFFu + ((x.u >> 16) & 1u);
  return (short)(r >> 16);
}
__device__ __forceinline__ float b2f(short s) {   // bf16 -> f32
  union { unsigned u; float f; } x; x.u = ((unsigned)(unsigned short)s) << 16;
  return x.f;
}

#define WT_ELEMS   (9 * 128 * 128)     // wT[k][o][c]
#define WOFF_ELEMS (9 * 32 * 128)      // wOffT[k][o(pad32)][c]
#define XT_BYTES   (8u * 4096u * 128u * 2u)   // x_t[b][y*64+x][c] bf16 = 8 MB

// ---- prep: reorder weights to tap-major bf16 ----
__global__ __launch_bounds__(256) void prep_w(
    const float* __restrict__ w_off, const float* __restrict__ w_dcn,
    short* __restrict__ wT, short* __restrict__ wOffT)
{
  int t = blockIdx.x * 256 + threadIdx.x;
  int stride = gridDim.x * 256;
  for (int i = t; i < WT_ELEMS; i += stride) {
    int k = i >> 14, r = i & 16383, o = r >> 7, c = r & 127;
    wT[i] = f2b(w_dcn[o * 1152 + c * 9 + k]);
  }
  for (int i = t; i < WOFF_ELEMS; i += stride) {
    int k = i >> 12, r = i & 4095, o = r >> 7, c = r & 127;
    wOffT[i] = (o < 18) ? f2b(w_off[o * 1152 + c * 9 + k]) : (short)0;
  }
}

// ---- transpose x[b][c][y][w] f32 -> x_t[b][y][w][c] bf16 ----
__global__ __launch_bounds__(256) void transp(
    const float* __restrict__ xg, short* __restrict__ xt)
{
  __shared__ float tile[32][65];
  const int bid = blockIdx.x;
  const int b = bid >> 6, y = bid & 63;
  const int t = threadIdx.x;
  const float* src = xg + ((size_t)b << 19) + y * 64;
  short*       dst = xt + ((size_t)b << 19) + (size_t)y * 8192;

  for (int ct = 0; ct < 4; ++ct) {
    __syncthreads();
    int c_l = t >> 3, w0 = (t & 7) * 8;
    const float* p = src + (size_t)(ct * 32 + c_l) * 4096 + w0;
    f32x4 a0 = *(const f32x4*)p;
    f32x4 a1 = *(const f32x4*)(p + 4);
    #pragma unroll
    for (int i = 0; i < 4; ++i) { tile[c_l][w0 + i] = a0[i]; tile[c_l][w0 + 4 + i] = a1[i]; }
    __syncthreads();
    int w = t >> 2, j0 = (t & 3) * 8;
    b16x8 pk;
    #pragma unroll
    for (int j = 0; j < 8; ++j) pk[j] = f2b(tile[j0 + j][w]);
    *(b16x8*)(dst + w * 128 + ct * 32 + j0) = pk;
  }
}

// ---------- helpers for the pipelined main kernel ----------
__device__ __forceinline__ void gather8(const short* xb, const i32x4* idxA,
                                        int k, int px_s, int cg, b16x8 (&g)[8]) {
  i32x4 iv = idxA[k * 32 + px_s];
  const short* r0 = xb + (size_t)iv[0] * 128;
  const short* r1 = xb + (size_t)iv[1] * 128;
  const short* r2 = xb + (size_t)iv[2] * 128;
  const short* r3 = xb + (size_t)iv[3] * 128;
  int c0 = cg * 8, c1 = 64 + cg * 8;
  g[0] = *(const b16x8*)(r0 + c0);  g[1] = *(const b16x8*)(r0 + c1);
  g[2] = *(const b16x8*)(r1 + c0);  g[3] = *(const b16x8*)(r1 + c1);
  g[4] = *(const b16x8*)(r2 + c0);  g[5] = *(const b16x8*)(r2 + c1);
  g[6] = *(const b16x8*)(r3 + c0);  g[7] = *(const b16x8*)(r3 + c1);
}

__device__ __forceinline__ void lerp_write(char* sbuf, const f32x4* wtA,
                                           int k, int px_s, int cg, const b16x8 (&g)[8]) {
  f32x4 wv = wtA[k * 32 + px_s];
  #pragma unroll
  for (int it = 0; it < 2; ++it) {
    b16x8 pk;
    #pragma unroll
    for (int j = 0; j < 8; ++j) {
      float v = wv[0] * b2f(g[0 + it][j]) + wv[1] * b2f(g[2 + it][j]) +
                wv[2] * b2f(g[4 + it][j]) + wv[3] * b2f(g[6 + it][j]);
      pk[j] = f2b(v);
    }
    int c0 = it * 64 + cg * 8;
    *(b16x8*)(sbuf + px_s * 256 + ((c0 * 2) ^ ((px_s & 7) << 4))) = pk;
  }
}

__device__ __forceinline__ void mfma_tap(const char* sbuf, const short* wk,
                                         int l15, int l4,
                                         f32x4& a00, f32x4& a01, f32x4& a10, f32x4& a11) {
  #pragma unroll
  for (int kk = 0; kk < 4; ++kk) {
    int cf = kk * 32 + l4 * 8;
    b16x8 w0 = *(const b16x8*)(wk + l15 * 128 + cf);
    b16x8 w1 = *(const b16x8*)(wk + (l15 + 16) * 128 + cf);
    b16x8 b0 = *(const b16x8*)(sbuf + l15 * 256        + ((cf * 2) ^ ((l15 & 7) << 4)));
    b16x8 b1 = *(const b16x8*)(sbuf + (16 + l15) * 256 + ((cf * 2) ^ ((l15 & 7) << 4)));
    a00 = __builtin_amdgcn_mfma_f32_16x16x32_bf16(w0, b0, a00, 0, 0, 0);
    a01 = __builtin_amdgcn_mfma_f32_16x16x32_bf16(w0, b1, a01, 0, 0, 0);
    a10 = __builtin_amdgcn_mfma_f32_16x16x32_bf16(w1, b0, a10, 0, 0, 0);
    a11 = __builtin_amdgcn_mfma_f32_16x16x32_bf16(w1, b1, a11, 0, 0, 0);
  }
}

// ---- fused deformable conv, MFMA, pipelined ----
// block = 32 px (b, ho, wo0..wo0+31), 256 threads = 4 waves.
__global__ __launch_bounds__(256, 4) void dcn_mfma(
    const short* __restrict__ xt, const float* __restrict__ b_off,
    const short* __restrict__ wT, const short* __restrict__ wOffT,
    float* __restrict__ out)
{
  // arena: phase1 = window W[102 pos][128c] bf16 swizzled (26112 B)
  //        phase2 = sS0(8192) | sS1(8192) | idxA(4608) | wtA(4608)  (25600 B)
  __shared__ __align__(16) char  arena[26112];
  __shared__ __align__(16) float offT[32 * 32];

  char*  sW   = arena;
  char*  sS0  = arena;
  char*  sS1  = arena + 8192;
  i32x4* idxA = (i32x4*)(arena + 16384);
  f32x4* wtA  = (f32x4*)(arena + 16384 + 4608);

  const int tid  = threadIdx.x;
  const int lane = tid & 63;
  const int wv_  = tid >> 6;
  const int bid  = blockIdx.x;
  const int swz  = (bid & 7) * 128 + (bid >> 3);   // batch -> one XCD (L2 locality)
  const int b    = swz >> 7;
  const int ho   = (swz >> 1) & 63;
  const int wo0  = (swz & 1) * 32;

  const int px_s = tid >> 3;       // 0..31
  const int cg   = tid & 7;        // 0..7
  const int l15  = lane & 15;
  const int l4   = lane >> 4;

  const short* xb = xt + ((size_t)b << 19);

  // ---- stage phase-1 window: 3 rows x 34 cols x 128 ch ----
  #pragma unroll
  for (int i = 0; i < 7; ++i) {
    int s = tid + i * 256;
    if (s < 1632) {                       // 102 positions * 16 chunks
      int p = s >> 4, cc = s & 15;
      int py = p / 34, pxw = p - py * 34;
      int y = ho - 1 + py, xw = wo0 + pxw - 1;
      bool v = ((unsigned)y < 64u) && ((unsigned)xw < 64u);
      b16x8 q = {0,0,0,0,0,0,0,0};
      if (v) q = *(const b16x8*)(xb + ((size_t)(y * 64 + xw) << 7) + cc * 8);
      *(b16x8*)(sW + p * 256 + ((cc * 16) ^ ((p & 7) << 4))) = q;
    }
  }
  __syncthreads();

  // ---- phase 1: offset conv, 36 MFMA straight, no barriers ----
  f32x4 accP = {0.f, 0.f, 0.f, 0.f};
  const int fo = wv_ >> 1, fp = wv_ & 1;
  {
    const int bpx = fp * 16 + l15;
    #pragma unroll
    for (int k = 0; k < 9; ++k) {
      int ky = k / 3, kx = k - ky * 3;
      int p  = ky * 34 + bpx + kx;
      const short* wk = wOffT + k * 4096;
      #pragma unroll
      for (int kk = 0; kk < 4; ++kk) {
        int cf = kk * 32 + l4 * 8;
        b16x8 a  = *(const b16x8*)(wk + (fo * 16 + l15) * 128 + cf);
        b16x8 bb = *(const b16x8*)(sW + p * 256 + ((cf * 2) ^ ((p & 7) << 4)));
        accP = __builtin_amdgcn_mfma_f32_16x16x32_bf16(a, bb, accP, 0, 0, 0);
      }
    }
  }
  {
    int px = fp * 16 + l15;
    int ob = fo * 16 + l4 * 4;
    #pragma unroll
    for (int r = 0; r < 4; ++r)
      offT[(ob + r) * 32 + px] = accP[r];
  }
  __syncthreads();   // all phase-1 window reads done; offT visible

  // ---- tables for ALL 9 taps (overwrites window region - safe after barrier) ----
  #pragma unroll
  for (int i = 0; i < 2; ++i) {
    int item = tid + i * 256;
    if (item < 288) {
      int k = item >> 5, px = item & 31;
      int ky = k / 3, kx = k - ky * 3;
      float dy = offT[(2 * k) * 32 + px]     + b_off[2 * k];
      float dx = offT[(2 * k + 1) * 32 + px] + b_off[2 * k + 1];
      float yy = (float)(ho - 1 + ky) + dy;
      float xx = (float)(wo0 + px - 1 + kx) + dx;
      float y0f = floorf(yy), x0f = floorf(xx);
      float wy = yy - y0f, wx = xx - x0f;
      int y0 = (int)y0f, x0 = (int)x0f;
      int y1 = y0 + 1, x1 = x0 + 1;
      int cy0 = min(max(y0, 0), 63), cx0 = min(max(x0, 0), 63);
      int cy1 = min(max(y1, 0), 63), cx1 = min(max(x1, 0), 63);
      float vy0 = ((unsigned)y0 < 64u) ? 1.f : 0.f;
      float vy1 = ((unsigned)y1 < 64u) ? 1.f : 0.f;
      float vx0 = ((unsigned)x0 < 64u) ? 1.f : 0.f;
      float vx1 = ((unsigned)x1 < 64u) ? 1.f : 0.f;
      i32x4 iv; iv[0] = cy0*64+cx0; iv[1] = cy0*64+cx1; iv[2] = cy1*64+cx0; iv[3] = cy1*64+cx1;
      f32x4 wvv;
      wvv[0] = (1.f - wy) * (1.f - wx) * vy0 * vx0;
      wvv[1] = (1.f - wy) * wx         * vy0 * vx1;
      wvv[2] = wy         * (1.f - wx) * vy1 * vx0;
      wvv[3] = wy         * wx         * vy1 * vx1;
      idxA[item] = iv; wtA[item] = wvv;
    }
  }
  __syncthreads();   // tables ready

  // ---- phase 2: pipelined sample + contract ----
  f32x4 acc00 = {0,0,0,0}, acc01 = {0,0,0,0}, acc10 = {0,0,0,0}, acc11 = {0,0,0,0};
  const short* wbase = wT + (wv_ * 32) * 128;   // wave's 32-o slice
  b16x8 gA[8], gB[8];

  gather8(xb, idxA, 0, px_s, cg, gA);

#define STEP(K, GCUR, GNXT, SBUF)                                         \
  {                                                                       \
    if ((K) < 8) gather8(xb, idxA, (K) + 1, px_s, cg, GNXT);              \
    lerp_write(SBUF, wtA, (K), px_s, cg, GCUR);                           \
    __syncthreads();                                                      \
    mfma_tap(SBUF, wbase + (K) * 16384, l15, l4, acc00, acc01, acc10, acc11); \
  }

  STEP(0, gA, gB, sS0)
  STEP(1, gB, gA, sS1)
  STEP(2, gA, gB, sS0)
  STEP(3, gB, gA, sS1)
  STEP(4, gA, gB, sS0)
  STEP(5, gB, gA, sS1)
  STEP(6, gA, gB, sS0)
  STEP(7, gB, gA, sS1)
  STEP(8, gA, gB, sS0)
#undef STEP

  // ---- epilogue ----
  {
    size_t base = ((size_t)b * 128) * 4096 + (size_t)ho * 64 + wo0;
    int o0 = wv_ * 32 + l4 * 4;
    #pragma unroll
    for (int r = 0; r < 4; ++r) {
      out[base + (size_t)(o0 + r) * 4096 + l15]           = acc00[r];
      out[base + (size_t)(o0 + r) * 4096 + 16 + l15]      = acc01[r];
      out[base + (size_t)(o0 + 16 + r) * 4096 + l15]      = acc10[r];
      out[base + (size_t)(o0 + 16 + r) * 4096 + 16 + l15] = acc11[r];
    }
  }
}

extern "C" void kernel_launch(void* const* d_in, const int* in_sizes, int n_in,
                              void* d_out, int out_size, void* d_ws, size_t ws_size,
                              hipStream_t stream) {
  const float* x     = (const float*)d_in[0];
  const float* w_off = (const float*)d_in[1];
  const float* b_off = (const float*)d_in[2];
  const float* w_dcn = (const float*)d_in[3];
  float* out = (float*)d_out;

  short* xt    = (short*)d_ws;                                    // 8,388,608 B
  short* wT    = (short*)((char*)d_ws + XT_BYTES);                // 294,912 B
  short* wOffT = (short*)((char*)d_ws + XT_BYTES + WT_ELEMS * 2); // 73,728 B

  hipLaunchKernelGGL(prep_w,   dim3(64),   dim3(256), 0, stream, w_off, w_dcn, wT, wOffT);
  hipLaunchKernelGGL(transp,   dim3(512),  dim3(256), 0, stream, x, xt);
  hipLaunchKernelGGL(dcn_mfma, dim3(1024), dim3(256), 0, stream, xt, b_off, wT, wOffT, out);
}